// Round 2
// baseline (98.342 us; speedup 1.0000x reference)
//
#include <hip/hip_runtime.h>

// SelfAttentionHead: B=16, T=1024, C=768, H=64, fp32 in/out, causal softmax.
// wtrans: W -> Wt[192][768] f16 (col-major per output column) for direct B-frag loads.
// proj:   barrier-free, LDS-free; per-lane A-frags from x, B-frags from Wt (L2).
//         V is stored transposed (Vt[b][d][t]) so attn needs no in-loop transpose.
// attn:   flash-style causal, 64-row q-tiles, online softmax.

typedef _Float16 half8 __attribute__((ext_vector_type(8)));
typedef _Float16 half4 __attribute__((ext_vector_type(4)));
typedef float float4v __attribute__((ext_vector_type(4)));

#define NB   16
#define NT   1024
#define NC   768
#define NH   64

// ---------------------------------------------------------------------------
// Wt[m*64+col][k] = Wm[k][col], m in {0:Q, 1:K, 2:V}. Grid (48,3) x 256.
// ---------------------------------------------------------------------------
__global__ __launch_bounds__(256) void wtrans_kernel(
    const float* __restrict__ Wq, const float* __restrict__ Wk,
    const float* __restrict__ Wv, _Float16* __restrict__ Wt)
{
    __shared__ float tile[16][68];
    const int m = blockIdx.y;
    const float* W = (m == 0) ? Wq : (m == 1) ? Wk : Wv;
    const int s = blockIdx.x;             // 16-row k-slab
    const int t = threadIdx.x;
    {
        const int kr = t >> 4, c4 = (t & 15) * 4;
        float4v v = *(const float4v*)(W + (size_t)(s * 16 + kr) * NH + c4);
        tile[kr][c4 + 0] = v[0]; tile[kr][c4 + 1] = v[1];
        tile[kr][c4 + 2] = v[2]; tile[kr][c4 + 3] = v[3];
    }
    __syncthreads();
    const int col = t >> 2, j = t & 3;
    half4 h;
#pragma unroll
    for (int i = 0; i < 4; ++i) h[i] = (_Float16)tile[j * 4 + i][col];
    *(half4*)(Wt + (size_t)(m * 64 + col) * NC + s * 16 + j * 4) = h;
}

// ---------------------------------------------------------------------------
// proj: grid 512 x 512 thr (8 waves). Wave (wm,wn): 16 rows (m0=bid*32+wm*16),
// 48 cols (gcol0=wn*48) of concatenated [Q|K|V]. No LDS, no barriers.
// ---------------------------------------------------------------------------
__global__ __launch_bounds__(512, 4) void proj_kernel(
    const float* __restrict__ x, const _Float16* __restrict__ Wt,
    _Float16* __restrict__ Qb, _Float16* __restrict__ Kb,
    _Float16* __restrict__ Vt)
{
    const int t   = threadIdx.x;
    const int wid = t >> 6, lane = t & 63;
    const int l15 = lane & 15, lhi = lane >> 4;
    const int wn  = wid & 3,  wm  = wid >> 2;
    const int m0  = blockIdx.x * 32 + wm * 16;
    const int gcol0 = wn * 48;

    const float*    xp = x  + (size_t)(m0 + l15) * NC + lhi * 8;
    const _Float16* wp = Wt + (size_t)(gcol0 + l15) * NC + lhi * 8;

    float4v acc[3];
#pragma unroll
    for (int j = 0; j < 3; ++j) acc[j] = (float4v){0.f, 0.f, 0.f, 0.f};

#pragma unroll 4
    for (int kc = 0; kc < 24; ++kc) {
        float4v xa = *(const float4v*)(xp + kc * 32);
        float4v xb = *(const float4v*)(xp + kc * 32 + 4);
        half8 b0 = *(const half8*)(wp + kc * 32);
        half8 b1 = *(const half8*)(wp + 16 * NC + kc * 32);
        half8 b2 = *(const half8*)(wp + 32 * NC + kc * 32);
        half8 a;
        a[0] = (_Float16)xa[0]; a[1] = (_Float16)xa[1];
        a[2] = (_Float16)xa[2]; a[3] = (_Float16)xa[3];
        a[4] = (_Float16)xb[0]; a[5] = (_Float16)xb[1];
        a[6] = (_Float16)xb[2]; a[7] = (_Float16)xb[3];
        acc[0] = __builtin_amdgcn_mfma_f32_16x16x32_f16(a, b0, acc[0], 0, 0, 0);
        acc[1] = __builtin_amdgcn_mfma_f32_16x16x32_f16(a, b1, acc[1], 0, 0, 0);
        acc[2] = __builtin_amdgcn_mfma_f32_16x16x32_f16(a, b2, acc[2], 0, 0, 0);
    }

#pragma unroll
    for (int nf = 0; nf < 3; ++nf) {
        const int gc  = gcol0 + nf * 16;
        const int sel = gc >> 6;
        const int col = (gc & 63) + l15;
        const int row0 = m0 + lhi * 4;
        if (sel == 2) {
            // V stored transposed: Vt[(b*64+col)*1024 + t], 4 consecutive tokens
            const int bb = row0 >> 10, tt = row0 & 1023;
            half4 h;
#pragma unroll
            for (int r = 0; r < 4; ++r) h[r] = (_Float16)acc[nf][r];
            *(half4*)(Vt + ((size_t)(bb * 64 + col)) * NT + tt) = h;
        } else {
            _Float16* D = (sel == 0) ? Qb : Kb;
#pragma unroll
            for (int r = 0; r < 4; ++r)
                D[(size_t)(row0 + r) * NH + col] = (_Float16)acc[nf][r];
        }
    }
}

// ---------------------------------------------------------------------------
// Flash attention, causal. Grid (16 q-tiles, 16 batches), 256 thr = 4 waves.
// ---------------------------------------------------------------------------
__global__ __launch_bounds__(256) void attn_kernel(
    const _Float16* __restrict__ Qb, const _Float16* __restrict__ Kb,
    const _Float16* __restrict__ Vt, float* __restrict__ out)
{
    __shared__ _Float16 Ql[64][72];
    __shared__ _Float16 Kl[64][72];
    __shared__ _Float16 Vl[64][72];      // Vl[d][key] (already transposed in ws)
    __shared__ _Float16 Pl[4][16][72];   // per-wave P buffer

    const int t = threadIdx.x, wid = t >> 6, lane = t & 63;
    const int l15 = lane & 15, lhi = lane >> 4;
    const int qi = blockIdx.x, b = blockIdx.y;
    const int qbase = qi * 64;
    const int srow = t >> 2, sc0 = (t & 3) * 16;

    {   // stage Q tile once
        const _Float16* src = Qb + ((size_t)(b * NT + qbase + srow)) * NH + sc0;
        *(half8*)&Ql[srow][sc0]     = *(const half8*)src;
        *(half8*)&Ql[srow][sc0 + 8] = *(const half8*)(src + 8);
    }
    __syncthreads();
    half8 aq[2];
    aq[0] = *(const half8*)&Ql[wid * 16 + l15][lhi * 8];
    aq[1] = *(const half8*)&Ql[wid * 16 + l15][32 + lhi * 8];

    float4v o[4];
#pragma unroll
    for (int nf = 0; nf < 4; ++nf) o[nf] = (float4v){0.f, 0.f, 0.f, 0.f};
    float mrow[4], lrow[4];
#pragma unroll
    for (int r = 0; r < 4; ++r) { mrow[r] = -1e30f; lrow[r] = 0.f; }

    for (int jt = 0; jt <= qi; ++jt) {
        // issue staging loads early (K row-major; V already [d][t] in global)
        const _Float16* ksrc = Kb + ((size_t)(b * NT + jt * 64 + srow)) * NH + sc0;
        const _Float16* vsrc = Vt + ((size_t)(b * 64 + srow)) * NT + jt * 64 + sc0;
        half8 k0 = *(const half8*)ksrc;
        half8 k1 = *(const half8*)(ksrc + 8);
        half8 v0 = *(const half8*)vsrc;
        half8 v1 = *(const half8*)(vsrc + 8);
        __syncthreads();   // previous tile's K/V reads done
        *(half8*)&Kl[srow][sc0]     = k0;
        *(half8*)&Kl[srow][sc0 + 8] = k1;
        *(half8*)&Vl[srow][sc0]     = v0;
        *(half8*)&Vl[srow][sc0 + 8] = v1;
        __syncthreads();

        // S = Q K^T
        float4v s[4];
#pragma unroll
        for (int nf = 0; nf < 4; ++nf) {
            half8 bk0 = *(const half8*)&Kl[nf * 16 + l15][lhi * 8];
            half8 bk1 = *(const half8*)&Kl[nf * 16 + l15][32 + lhi * 8];
            float4v sv = (float4v){0.f, 0.f, 0.f, 0.f};
            sv = __builtin_amdgcn_mfma_f32_16x16x32_f16(aq[0], bk0, sv, 0, 0, 0);
            sv = __builtin_amdgcn_mfma_f32_16x16x32_f16(aq[1], bk1, sv, 0, 0, 0);
            s[nf] = sv;
        }

        // scale + causal mask + row max
        const bool diag = (jt == qi);
        float pm[4] = {-1e30f, -1e30f, -1e30f, -1e30f};
#pragma unroll
        for (int nf = 0; nf < 4; ++nf)
#pragma unroll
            for (int r = 0; r < 4; ++r) {
                float v = s[nf][r] * 0.125f;   // 1/sqrt(64)
                if (diag) {
                    const int key = nf * 16 + l15;
                    const int qr  = wid * 16 + lhi * 4 + r;
                    if (key > qr) v = -1e30f;
                }
                s[nf][r] = v;
                pm[r] = fmaxf(pm[r], v);
            }
#pragma unroll
        for (int mask = 1; mask < 16; mask <<= 1)
#pragma unroll
            for (int r = 0; r < 4; ++r)
                pm[r] = fmaxf(pm[r], __shfl_xor(pm[r], mask));

        float mnew[4], esc[4], ssum[4];
#pragma unroll
        for (int r = 0; r < 4; ++r) {
            mnew[r] = fmaxf(mrow[r], pm[r]);
            esc[r]  = __expf(mrow[r] - mnew[r]);
            ssum[r] = 0.f;
        }
#pragma unroll
        for (int nf = 0; nf < 4; ++nf)
#pragma unroll
            for (int r = 0; r < 4; ++r) {
                const float p = __expf(s[nf][r] - mnew[r]);
                ssum[r] += p;
                Pl[wid][lhi * 4 + r][nf * 16 + l15] = (_Float16)p;
            }
#pragma unroll
        for (int mask = 1; mask < 16; mask <<= 1)
#pragma unroll
            for (int r = 0; r < 4; ++r)
                ssum[r] += __shfl_xor(ssum[r], mask);
#pragma unroll
        for (int r = 0; r < 4; ++r) {
            lrow[r] = lrow[r] * esc[r] + ssum[r];
            mrow[r] = mnew[r];
        }
#pragma unroll
        for (int nf = 0; nf < 4; ++nf)
#pragma unroll
            for (int r = 0; r < 4; ++r)
                o[nf][r] *= esc[r];

        // O += P V   (P via per-wave LDS round-trip; within-wave, no barrier)
#pragma unroll
        for (int ks = 0; ks < 2; ++ks) {
            half8 pa = *(const half8*)&Pl[wid][l15][ks * 32 + lhi * 8];
#pragma unroll
            for (int nf = 0; nf < 4; ++nf) {
                half8 bv = *(const half8*)&Vl[nf * 16 + l15][ks * 32 + lhi * 8];
                o[nf] = __builtin_amdgcn_mfma_f32_16x16x32_f16(pa, bv, o[nf], 0, 0, 0);
            }
        }
    }

    // epilogue: normalize and store fp32
#pragma unroll
    for (int nf = 0; nf < 4; ++nf)
#pragma unroll
        for (int r = 0; r < 4; ++r) {
            const int row = qbase + wid * 16 + lhi * 4 + r;
            out[((size_t)(b * NT + row)) * NH + nf * 16 + l15] = o[nf][r] / lrow[r];
        }
}

extern "C" void kernel_launch(void* const* d_in, const int* in_sizes, int n_in,
                              void* d_out, int out_size, void* d_ws, size_t ws_size,
                              hipStream_t stream) {
    const float* x  = (const float*)d_in[0];
    const float* Wk = (const float*)d_in[1];
    const float* Wq = (const float*)d_in[2];
    const float* Wv = (const float*)d_in[3];

    _Float16* Qb = (_Float16*)d_ws;                        // 2 MB
    _Float16* Kb = Qb + (size_t)NB * NT * NH;              // 2 MB
    _Float16* Vt = Kb + (size_t)NB * NT * NH;              // 2 MB (transposed V)
    _Float16* Wt = Vt + (size_t)NB * NT * NH;              // 288 KB

    wtrans_kernel<<<dim3(48, 3), dim3(256), 0, stream>>>(Wq, Wk, Wv, Wt);
    proj_kernel<<<dim3(512), dim3(512), 0, stream>>>(x, Wt, Qb, Kb, Vt);
    attn_kernel<<<dim3(16, 16), dim3(256), 0, stream>>>(Qb, Kb, Vt, (float*)d_out);
}

// Round 3
// 63.706 us; speedup vs baseline: 1.5437x; 1.5437x over previous
//
#include <hip/hip_runtime.h>

// SelfAttentionHead: B=16, T=1024, C=768, H=64, fp32 in/out, causal softmax.
// wtrans: W -> Wt[192][768] f16 (col-major per output column) for direct B-frag loads.
// proj:   LDS-staged f16 GEMM, BM=32/BK=64, grid 512x256thr (2 blocks/CU),
//         register-pipelined x and Wt prefetch. V stored transposed (Vt[b][d][t]).
// attn:   flash-style causal, 64-row q-tiles, online softmax.

typedef _Float16 half8 __attribute__((ext_vector_type(8)));
typedef _Float16 half4 __attribute__((ext_vector_type(4)));
typedef float float4v __attribute__((ext_vector_type(4)));

#define NB   16
#define NT   1024
#define NC   768
#define NH   64

// ---------------------------------------------------------------------------
// Wt[m*64+col][k] = Wm[k][col], m in {0:Q, 1:K, 2:V}. Grid (48,3) x 256.
// ---------------------------------------------------------------------------
__global__ __launch_bounds__(256) void wtrans_kernel(
    const float* __restrict__ Wq, const float* __restrict__ Wk,
    const float* __restrict__ Wv, _Float16* __restrict__ Wt)
{
    __shared__ float tile[16][68];
    const int m = blockIdx.y;
    const float* W = (m == 0) ? Wq : (m == 1) ? Wk : Wv;
    const int s = blockIdx.x;             // 16-row k-slab
    const int t = threadIdx.x;
    {
        const int kr = t >> 4, c4 = (t & 15) * 4;
        float4v v = *(const float4v*)(W + (size_t)(s * 16 + kr) * NH + c4);
        tile[kr][c4 + 0] = v[0]; tile[kr][c4 + 1] = v[1];
        tile[kr][c4 + 2] = v[2]; tile[kr][c4 + 3] = v[3];
    }
    __syncthreads();
    const int col = t >> 2, j = t & 3;
    half4 h;
#pragma unroll
    for (int i = 0; i < 4; ++i) h[i] = (_Float16)tile[j * 4 + i][col];
    *(half4*)(Wt + (size_t)(m * 64 + col) * NC + s * 16 + j * 4) = h;
}

// ---------------------------------------------------------------------------
// proj: grid 512 x 256 thr (4 waves). Block: 32 rows x 192 cols.
// Wave wn owns cols wn*48..wn*48+48 (3 n-frags) over all 32 rows (2 m-frags).
// x staged to LDS as f16 (BK=64); Wt B-frags straight from L2.
// ---------------------------------------------------------------------------
__global__ __launch_bounds__(256) void proj_kernel(
    const float* __restrict__ x, const _Float16* __restrict__ Wt,
    _Float16* __restrict__ Qb, _Float16* __restrict__ Kb,
    _Float16* __restrict__ Vt)
{
    __shared__ _Float16 xl[32][68];   // 136B row stride: even bank spread

    const int t   = threadIdx.x;
    const int wid = t >> 6, lane = t & 63;
    const int l15 = lane & 15, lhi = lane >> 4;
    const int m0  = blockIdx.x * 32;
    const int srow = t >> 3, sc0 = (t & 7) * 8;   // staging: 8 consecutive f32

    const float*    xsrc  = x  + (size_t)(m0 + srow) * NC + sc0;
    const _Float16* wbase = Wt + (size_t)(wid * 48 + l15) * NC + lhi * 8;

    float4v acc[2][3];
#pragma unroll
    for (int i = 0; i < 2; ++i)
#pragma unroll
        for (int j = 0; j < 3; ++j)
            acc[i][j] = (float4v){0.f, 0.f, 0.f, 0.f};

    // preload kc=0
    float4v g0 = *(const float4v*)(xsrc);
    float4v g1 = *(const float4v*)(xsrc + 4);
    half8 bf[3][2];
#pragma unroll
    for (int nf = 0; nf < 3; ++nf)
#pragma unroll
        for (int ks = 0; ks < 2; ++ks)
            bf[nf][ks] = *(const half8*)(wbase + (size_t)nf * 16 * NC + ks * 32);

    for (int kc = 0; kc < 12; ++kc) {
        __syncthreads();   // previous iteration's LDS reads done
        {
            half8 h;
            h[0] = (_Float16)g0[0]; h[1] = (_Float16)g0[1];
            h[2] = (_Float16)g0[2]; h[3] = (_Float16)g0[3];
            h[4] = (_Float16)g1[0]; h[5] = (_Float16)g1[1];
            h[6] = (_Float16)g1[2]; h[7] = (_Float16)g1[3];
            *(half8*)&xl[srow][sc0] = h;
        }
        __syncthreads();

        half8 bcur[3][2];
#pragma unroll
        for (int nf = 0; nf < 3; ++nf)
#pragma unroll
            for (int ks = 0; ks < 2; ++ks) bcur[nf][ks] = bf[nf][ks];

        if (kc < 11) {   // issue next-iter globals early; in flight across MFMAs
            g0 = *(const float4v*)(xsrc + (kc + 1) * 64);
            g1 = *(const float4v*)(xsrc + (kc + 1) * 64 + 4);
#pragma unroll
            for (int nf = 0; nf < 3; ++nf)
#pragma unroll
                for (int ks = 0; ks < 2; ++ks)
                    bf[nf][ks] = *(const half8*)(wbase + (size_t)nf * 16 * NC
                                                 + (kc + 1) * 64 + ks * 32);
        }

        half8 af[2][2];
#pragma unroll
        for (int mf = 0; mf < 2; ++mf)
#pragma unroll
            for (int ks = 0; ks < 2; ++ks)
                af[mf][ks] = *(const half8*)&xl[mf * 16 + l15][ks * 32 + lhi * 8];

#pragma unroll
        for (int ks = 0; ks < 2; ++ks)
#pragma unroll
            for (int mf = 0; mf < 2; ++mf)
#pragma unroll
                for (int nf = 0; nf < 3; ++nf)
                    acc[mf][nf] = __builtin_amdgcn_mfma_f32_16x16x32_f16(
                        af[mf][ks], bcur[nf][ks], acc[mf][nf], 0, 0, 0);
    }

#pragma unroll
    for (int nf = 0; nf < 3; ++nf) {
        const int gc  = wid * 48 + nf * 16;
        const int sel = gc >> 6;
        const int col = (gc & 63) + l15;
#pragma unroll
        for (int mf = 0; mf < 2; ++mf) {
            const int row0 = m0 + mf * 16 + lhi * 4;
            if (sel == 2) {
                const int bb = row0 >> 10, tt = row0 & 1023;
                half4 h;
#pragma unroll
                for (int r = 0; r < 4; ++r) h[r] = (_Float16)acc[mf][nf][r];
                *(half4*)(Vt + ((size_t)(bb * 64 + col)) * NT + tt) = h;
            } else {
                _Float16* D = (sel == 0) ? Qb : Kb;
#pragma unroll
                for (int r = 0; r < 4; ++r)
                    D[(size_t)(row0 + r) * NH + col] = (_Float16)acc[mf][nf][r];
            }
        }
    }
}

// ---------------------------------------------------------------------------
// Flash attention, causal. Grid (16 q-tiles, 16 batches), 256 thr = 4 waves.
// ---------------------------------------------------------------------------
__global__ __launch_bounds__(256) void attn_kernel(
    const _Float16* __restrict__ Qb, const _Float16* __restrict__ Kb,
    const _Float16* __restrict__ Vt, float* __restrict__ out)
{
    __shared__ _Float16 Ql[64][72];
    __shared__ _Float16 Kl[64][72];
    __shared__ _Float16 Vl[64][72];      // Vl[d][key] (already transposed in ws)
    __shared__ _Float16 Pl[4][16][72];   // per-wave P buffer

    const int t = threadIdx.x, wid = t >> 6, lane = t & 63;
    const int l15 = lane & 15, lhi = lane >> 4;
    const int qi = blockIdx.x, b = blockIdx.y;
    const int qbase = qi * 64;
    const int srow = t >> 2, sc0 = (t & 3) * 16;

    {   // stage Q tile once
        const _Float16* src = Qb + ((size_t)(b * NT + qbase + srow)) * NH + sc0;
        *(half8*)&Ql[srow][sc0]     = *(const half8*)src;
        *(half8*)&Ql[srow][sc0 + 8] = *(const half8*)(src + 8);
    }
    __syncthreads();
    half8 aq[2];
    aq[0] = *(const half8*)&Ql[wid * 16 + l15][lhi * 8];
    aq[1] = *(const half8*)&Ql[wid * 16 + l15][32 + lhi * 8];

    float4v o[4];
#pragma unroll
    for (int nf = 0; nf < 4; ++nf) o[nf] = (float4v){0.f, 0.f, 0.f, 0.f};
    float mrow[4], lrow[4];
#pragma unroll
    for (int r = 0; r < 4; ++r) { mrow[r] = -1e30f; lrow[r] = 0.f; }

    for (int jt = 0; jt <= qi; ++jt) {
        // issue staging loads early (K row-major; V already [d][t] in global)
        const _Float16* ksrc = Kb + ((size_t)(b * NT + jt * 64 + srow)) * NH + sc0;
        const _Float16* vsrc = Vt + ((size_t)(b * 64 + srow)) * NT + jt * 64 + sc0;
        half8 k0 = *(const half8*)ksrc;
        half8 k1 = *(const half8*)(ksrc + 8);
        half8 v0 = *(const half8*)vsrc;
        half8 v1 = *(const half8*)(vsrc + 8);
        __syncthreads();   // previous tile's K/V reads done
        *(half8*)&Kl[srow][sc0]     = k0;
        *(half8*)&Kl[srow][sc0 + 8] = k1;
        *(half8*)&Vl[srow][sc0]     = v0;
        *(half8*)&Vl[srow][sc0 + 8] = v1;
        __syncthreads();

        // S = Q K^T
        float4v s[4];
#pragma unroll
        for (int nf = 0; nf < 4; ++nf) {
            half8 bk0 = *(const half8*)&Kl[nf * 16 + l15][lhi * 8];
            half8 bk1 = *(const half8*)&Kl[nf * 16 + l15][32 + lhi * 8];
            float4v sv = (float4v){0.f, 0.f, 0.f, 0.f};
            sv = __builtin_amdgcn_mfma_f32_16x16x32_f16(aq[0], bk0, sv, 0, 0, 0);
            sv = __builtin_amdgcn_mfma_f32_16x16x32_f16(aq[1], bk1, sv, 0, 0, 0);
            s[nf] = sv;
        }

        // scale + causal mask + row max
        const bool diag = (jt == qi);
        float pm[4] = {-1e30f, -1e30f, -1e30f, -1e30f};
#pragma unroll
        for (int nf = 0; nf < 4; ++nf)
#pragma unroll
            for (int r = 0; r < 4; ++r) {
                float v = s[nf][r] * 0.125f;   // 1/sqrt(64)
                if (diag) {
                    const int key = nf * 16 + l15;
                    const int qr  = wid * 16 + lhi * 4 + r;
                    if (key > qr) v = -1e30f;
                }
                s[nf][r] = v;
                pm[r] = fmaxf(pm[r], v);
            }
#pragma unroll
        for (int mask = 1; mask < 16; mask <<= 1)
#pragma unroll
            for (int r = 0; r < 4; ++r)
                pm[r] = fmaxf(pm[r], __shfl_xor(pm[r], mask));

        float mnew[4], esc[4], ssum[4];
#pragma unroll
        for (int r = 0; r < 4; ++r) {
            mnew[r] = fmaxf(mrow[r], pm[r]);
            esc[r]  = __expf(mrow[r] - mnew[r]);
            ssum[r] = 0.f;
        }
#pragma unroll
        for (int nf = 0; nf < 4; ++nf)
#pragma unroll
            for (int r = 0; r < 4; ++r) {
                const float p = __expf(s[nf][r] - mnew[r]);
                ssum[r] += p;
                Pl[wid][lhi * 4 + r][nf * 16 + l15] = (_Float16)p;
            }
#pragma unroll
        for (int mask = 1; mask < 16; mask <<= 1)
#pragma unroll
            for (int r = 0; r < 4; ++r)
                ssum[r] += __shfl_xor(ssum[r], mask);
#pragma unroll
        for (int r = 0; r < 4; ++r) {
            lrow[r] = lrow[r] * esc[r] + ssum[r];
            mrow[r] = mnew[r];
        }
#pragma unroll
        for (int nf = 0; nf < 4; ++nf)
#pragma unroll
            for (int r = 0; r < 4; ++r)
                o[nf][r] *= esc[r];

        // O += P V   (P via per-wave LDS round-trip; within-wave, no barrier)
#pragma unroll
        for (int ks = 0; ks < 2; ++ks) {
            half8 pa = *(const half8*)&Pl[wid][l15][ks * 32 + lhi * 8];
#pragma unroll
            for (int nf = 0; nf < 4; ++nf) {
                half8 bv = *(const half8*)&Vl[nf * 16 + l15][ks * 32 + lhi * 8];
                o[nf] = __builtin_amdgcn_mfma_f32_16x16x32_f16(pa, bv, o[nf], 0, 0, 0);
            }
        }
    }

    // epilogue: normalize and store fp32
#pragma unroll
    for (int nf = 0; nf < 4; ++nf)
#pragma unroll
        for (int r = 0; r < 4; ++r) {
            const int row = qbase + wid * 16 + lhi * 4 + r;
            out[((size_t)(b * NT + row)) * NH + nf * 16 + l15] = o[nf][r] / lrow[r];
        }
}

extern "C" void kernel_launch(void* const* d_in, const int* in_sizes, int n_in,
                              void* d_out, int out_size, void* d_ws, size_t ws_size,
                              hipStream_t stream) {
    const float* x  = (const float*)d_in[0];
    const float* Wk = (const float*)d_in[1];
    const float* Wq = (const float*)d_in[2];
    const float* Wv = (const float*)d_in[3];

    _Float16* Qb = (_Float16*)d_ws;                        // 2 MB
    _Float16* Kb = Qb + (size_t)NB * NT * NH;              // 2 MB
    _Float16* Vt = Kb + (size_t)NB * NT * NH;              // 2 MB (transposed V)
    _Float16* Wt = Vt + (size_t)NB * NT * NH;              // 288 KB

    wtrans_kernel<<<dim3(48, 3), dim3(256), 0, stream>>>(Wq, Wk, Wv, Wt);
    proj_kernel<<<dim3(512), dim3(256), 0, stream>>>(x, Wt, Qb, Kb, Vt);
    attn_kernel<<<dim3(16, 16), dim3(256), 0, stream>>>(Qb, Kb, Vt, (float*)d_out);
}

// Round 5
// 53.688 us; speedup vs baseline: 1.8317x; 1.1866x over previous
//
#include <hip/hip_runtime.h>

// SelfAttentionHead: B=16, T=1024, C=768, H=64, fp32 in/out, causal softmax.
// wtrans: W -> Wt[192][768] f16 for direct B-frag loads.
// proj:   LDS-staged f16 GEMM (unchanged from R3). V stored transposed Vt[b][d][t].
// attn:   barrier-free, LDS-free. One wave = 16 q-rows; K/V frags straight
//         from global (L2); swapped QK^T => in-register softmax; P transposed to
//         PV A-frags via cvt_pkrtz + lane shuffles. K reg-double-buffered.

typedef _Float16 half8 __attribute__((ext_vector_type(8)));
typedef _Float16 half4 __attribute__((ext_vector_type(4)));
typedef float float4v __attribute__((ext_vector_type(4)));

#define NB   16
#define NT   1024
#define NC   768
#define NH   64

// ---------------------------------------------------------------------------
// Wt[m*64+col][k] = Wm[k][col], m in {0:Q, 1:K, 2:V}. Grid (48,3) x 256.
// ---------------------------------------------------------------------------
__global__ __launch_bounds__(256) void wtrans_kernel(
    const float* __restrict__ Wq, const float* __restrict__ Wk,
    const float* __restrict__ Wv, _Float16* __restrict__ Wt)
{
    __shared__ float tile[16][68];
    const int m = blockIdx.y;
    const float* W = (m == 0) ? Wq : (m == 1) ? Wk : Wv;
    const int s = blockIdx.x;             // 16-row k-slab
    const int t = threadIdx.x;
    {
        const int kr = t >> 4, c4 = (t & 15) * 4;
        float4v v = *(const float4v*)(W + (size_t)(s * 16 + kr) * NH + c4);
        tile[kr][c4 + 0] = v[0]; tile[kr][c4 + 1] = v[1];
        tile[kr][c4 + 2] = v[2]; tile[kr][c4 + 3] = v[3];
    }
    __syncthreads();
    const int col = t >> 2, j = t & 3;
    half4 h;
#pragma unroll
    for (int i = 0; i < 4; ++i) h[i] = (_Float16)tile[j * 4 + i][col];
    *(half4*)(Wt + (size_t)(m * 64 + col) * NC + s * 16 + j * 4) = h;
}

// ---------------------------------------------------------------------------
// proj: grid 512 x 256 thr (4 waves). Block: 32 rows x 192 cols. (unchanged R3)
// ---------------------------------------------------------------------------
__global__ __launch_bounds__(256) void proj_kernel(
    const float* __restrict__ x, const _Float16* __restrict__ Wt,
    _Float16* __restrict__ Qb, _Float16* __restrict__ Kb,
    _Float16* __restrict__ Vt)
{
    __shared__ _Float16 xl[32][68];

    const int t   = threadIdx.x;
    const int wid = t >> 6, lane = t & 63;
    const int l15 = lane & 15, lhi = lane >> 4;
    const int m0  = blockIdx.x * 32;
    const int srow = t >> 3, sc0 = (t & 7) * 8;

    const float*    xsrc  = x  + (size_t)(m0 + srow) * NC + sc0;
    const _Float16* wbase = Wt + (size_t)(wid * 48 + l15) * NC + lhi * 8;

    float4v acc[2][3];
#pragma unroll
    for (int i = 0; i < 2; ++i)
#pragma unroll
        for (int j = 0; j < 3; ++j)
            acc[i][j] = (float4v){0.f, 0.f, 0.f, 0.f};

    float4v g0 = *(const float4v*)(xsrc);
    float4v g1 = *(const float4v*)(xsrc + 4);
    half8 bf[3][2];
#pragma unroll
    for (int nf = 0; nf < 3; ++nf)
#pragma unroll
        for (int ks = 0; ks < 2; ++ks)
            bf[nf][ks] = *(const half8*)(wbase + (size_t)nf * 16 * NC + ks * 32);

    for (int kc = 0; kc < 12; ++kc) {
        __syncthreads();
        {
            half8 h;
            h[0] = (_Float16)g0[0]; h[1] = (_Float16)g0[1];
            h[2] = (_Float16)g0[2]; h[3] = (_Float16)g0[3];
            h[4] = (_Float16)g1[0]; h[5] = (_Float16)g1[1];
            h[6] = (_Float16)g1[2]; h[7] = (_Float16)g1[3];
            *(half8*)&xl[srow][sc0] = h;
        }
        __syncthreads();

        half8 bcur[3][2];
#pragma unroll
        for (int nf = 0; nf < 3; ++nf)
#pragma unroll
            for (int ks = 0; ks < 2; ++ks) bcur[nf][ks] = bf[nf][ks];

        if (kc < 11) {
            g0 = *(const float4v*)(xsrc + (kc + 1) * 64);
            g1 = *(const float4v*)(xsrc + (kc + 1) * 64 + 4);
#pragma unroll
            for (int nf = 0; nf < 3; ++nf)
#pragma unroll
                for (int ks = 0; ks < 2; ++ks)
                    bf[nf][ks] = *(const half8*)(wbase + (size_t)nf * 16 * NC
                                                 + (kc + 1) * 64 + ks * 32);
        }

        half8 af[2][2];
#pragma unroll
        for (int mf = 0; mf < 2; ++mf)
#pragma unroll
            for (int ks = 0; ks < 2; ++ks)
                af[mf][ks] = *(const half8*)&xl[mf * 16 + l15][ks * 32 + lhi * 8];

#pragma unroll
        for (int ks = 0; ks < 2; ++ks)
#pragma unroll
            for (int mf = 0; mf < 2; ++mf)
#pragma unroll
                for (int nf = 0; nf < 3; ++nf)
                    acc[mf][nf] = __builtin_amdgcn_mfma_f32_16x16x32_f16(
                        af[mf][ks], bcur[nf][ks], acc[mf][nf], 0, 0, 0);
    }

#pragma unroll
    for (int nf = 0; nf < 3; ++nf) {
        const int gc  = wid * 48 + nf * 16;
        const int sel = gc >> 6;
        const int col = (gc & 63) + l15;
#pragma unroll
        for (int mf = 0; mf < 2; ++mf) {
            const int row0 = m0 + mf * 16 + lhi * 4;
            if (sel == 2) {
                const int bb = row0 >> 10, tt = row0 & 1023;
                half4 h;
#pragma unroll
                for (int r = 0; r < 4; ++r) h[r] = (_Float16)acc[mf][nf][r];
                *(half4*)(Vt + ((size_t)(bb * 64 + col)) * NT + tt) = h;
            } else {
                _Float16* D = (sel == 0) ? Qb : Kb;
#pragma unroll
                for (int r = 0; r < 4; ++r)
                    D[(size_t)(row0 + r) * NH + col] = (_Float16)acc[mf][nf][r];
            }
        }
    }
}

// ---------------------------------------------------------------------------
// attn: grid (16, 16) x 256 thr. Wave wid owns q-rows [qw*16, qw*16+16),
// qw = wid*16 + blockIdx.x (mixes heavy/light waves per block).
// No LDS, no barriers. Swapped QK^T: sT = mfma(K_frag, Q_frag) -> lane l15 = q.
// ---------------------------------------------------------------------------
__global__ __launch_bounds__(256) void attn_kernel(
    const _Float16* __restrict__ Qb, const _Float16* __restrict__ Kb,
    const _Float16* __restrict__ Vt, float* __restrict__ out)
{
    const int t = threadIdx.x, wid = t >> 6, lane = t & 63;
    const int l15 = lane & 15, lhi = lane >> 4;
    const int b = blockIdx.y;
    const int qw = wid * 16 + blockIdx.x;     // 0..63
    const int q0 = qw * 16;
    const int nt = (q0 >> 6) + 1;             // KV tiles of 64 rows
    const int qrel = (q0 & 63) + l15;         // q index within last tile, per lane

    // Q fragment (B-operand of swapped QK^T): lane l15 = q-row, elems = channel
    const _Float16* qsrc = Qb + ((size_t)(b * NT + q0 + l15)) * NH + lhi * 8;
    const half8 aq0 = *(const half8*)qsrc;
    const half8 aq1 = *(const half8*)(qsrc + 32);

    // per-lane global bases
    const _Float16* kptr = Kb + ((size_t)(b * NT + l15)) * NH + lhi * 8;
    const _Float16* vptr = Vt + ((size_t)(b * 64 + l15)) * NT + lhi * 8;

    float4v o[4];
#pragma unroll
    for (int nf = 0; nf < 4; ++nf) o[nf] = (float4v){0.f, 0.f, 0.f, 0.f};
    float m2 = -1e30f, lsum = 0.f;

    auto LOADK = [&](half8 (&bk)[8], int jt) {
#pragma unroll
        for (int kf = 0; kf < 4; ++kf)
#pragma unroll
            for (int ch = 0; ch < 2; ++ch)
                bk[kf * 2 + ch] = *(const half8*)(kptr
                    + ((size_t)(jt * 64 + kf * 16)) * NH + ch * 32);
    };

    auto STEP = [&](const half8 (&bk)[8], int jt, bool last) {
        // V fragments for this tile (used ~after softmax; issued first)
        half8 bv[8];
#pragma unroll
        for (int ks = 0; ks < 2; ++ks)
#pragma unroll
            for (int nf = 0; nf < 4; ++nf)
                bv[ks * 4 + nf] = *(const half8*)(vptr + (size_t)nf * 16 * NT
                                                  + jt * 64 + ks * 32);

        // S^T = K * Q^T : col = q = l15, row(kf) = k-sub = lhi*4+r
        float4v sT[4];
#pragma unroll
        for (int kf = 0; kf < 4; ++kf) {
            float4v sv = (float4v){0.f, 0.f, 0.f, 0.f};
            sv = __builtin_amdgcn_mfma_f32_16x16x32_f16(bk[kf * 2 + 0], aq0, sv, 0, 0, 0);
            sv = __builtin_amdgcn_mfma_f32_16x16x32_f16(bk[kf * 2 + 1], aq1, sv, 0, 0, 0);
            sT[kf] = sv;
        }

        // scale into log2 domain, causal mask, tile max (per lane: 16 k-values, one q)
        const float SC = 0.18033688f;   // 0.125 * log2(e)
        float p[4][4];
        float mt = -1e30f;
#pragma unroll
        for (int kf = 0; kf < 4; ++kf)
#pragma unroll
            for (int r = 0; r < 4; ++r) {
                float v = sT[kf][r] * SC;
                if (last) {
                    const int kpos = kf * 16 + lhi * 4 + r;
                    if (kpos > qrel) v = -1e30f;
                }
                p[kf][r] = v;
                mt = fmaxf(mt, v);
            }
        mt = fmaxf(mt, __shfl_xor(mt, 16));
        mt = fmaxf(mt, __shfl_xor(mt, 32));

        const float mnew = fmaxf(m2, mt);
        const float esc  = exp2f(m2 - mnew);
        float ps = 0.f;
#pragma unroll
        for (int kf = 0; kf < 4; ++kf)
#pragma unroll
            for (int r = 0; r < 4; ++r) {
                const float e = exp2f(p[kf][r] - mnew);
                p[kf][r] = e;
                ps += e;
            }
        ps += __shfl_xor(ps, 16);
        ps += __shfl_xor(ps, 32);
        lsum = lsum * esc + ps;
        m2 = mnew;

        // rescale O (O rows are q = lhi*4+r; esc lives at lane l15=q)
        float er[4];
#pragma unroll
        for (int r = 0; r < 4; ++r) er[r] = __shfl(esc, lhi * 4 + r);
#pragma unroll
        for (int nf = 0; nf < 4; ++nf)
#pragma unroll
            for (int r = 0; r < 4; ++r) o[nf][r] *= er[r];

        // pack P to f16 pairs: pk[kf][pr] covers k = kf*16+lhi*4+2pr+{0,1}
        unsigned int pk[4][2];
#pragma unroll
        for (int kf = 0; kf < 4; ++kf)
#pragma unroll
            for (int pr = 0; pr < 2; ++pr) {
                auto h2 = __builtin_amdgcn_cvt_pkrtz(p[kf][2 * pr], p[kf][2 * pr + 1]);
                pk[kf][pr] = __builtin_bit_cast(unsigned int, h2);
            }

        // transpose to PV A-frags via lane shuffles:
        // word m of pa[ks] (k = ks*32+lhi*8+2m+{0,1}) comes from
        // lane l15 + 16*((lhi&1)*2 + (m>>1)), reg pk[2ks + (lhi>>1)][m&1]
        const int sb = l15 + ((lhi & 1) * 2) * 16;
        const bool hi = (lhi >> 1) != 0;
#pragma unroll
        for (int ks = 0; ks < 2; ++ks) {
            unsigned int w[4];
#pragma unroll
            for (int m = 0; m < 4; ++m) {
                const int L = sb + ((m >> 1) << 4);
                const unsigned int wA = (unsigned int)__shfl((int)pk[2 * ks + 0][m & 1], L);
                const unsigned int wB = (unsigned int)__shfl((int)pk[2 * ks + 1][m & 1], L);
                w[m] = hi ? wB : wA;
            }
            union { unsigned int u[4]; half8 h; } cvt;
            cvt.u[0] = w[0]; cvt.u[1] = w[1]; cvt.u[2] = w[2]; cvt.u[3] = w[3];
            const half8 pa = cvt.h;
#pragma unroll
            for (int nf = 0; nf < 4; ++nf)
                o[nf] = __builtin_amdgcn_mfma_f32_16x16x32_f16(pa, bv[ks * 4 + nf],
                                                               o[nf], 0, 0, 0);
        }
    };

    half8 kA[8], kB[8];
    LOADK(kA, 0);
    int jt = 0;
    while (true) {
        if (jt + 1 < nt) LOADK(kB, jt + 1);
        STEP(kA, jt, jt == nt - 1);
        ++jt; if (jt == nt) break;
        if (jt + 1 < nt) LOADK(kA, jt + 1);
        STEP(kB, jt, jt == nt - 1);
        ++jt; if (jt == nt) break;
    }

    // epilogue: normalize, store fp32
    const float linv = 1.f / lsum;
    float lr[4];
#pragma unroll
    for (int r = 0; r < 4; ++r) lr[r] = __shfl(linv, lhi * 4 + r);
#pragma unroll
    for (int nf = 0; nf < 4; ++nf)
#pragma unroll
        for (int r = 0; r < 4; ++r) {
            const int row = q0 + lhi * 4 + r;
            out[((size_t)(b * NT + row)) * NH + nf * 16 + l15] = o[nf][r] * lr[r];
        }
}

extern "C" void kernel_launch(void* const* d_in, const int* in_sizes, int n_in,
                              void* d_out, int out_size, void* d_ws, size_t ws_size,
                              hipStream_t stream) {
    const float* x  = (const float*)d_in[0];
    const float* Wk = (const float*)d_in[1];
    const float* Wq = (const float*)d_in[2];
    const float* Wv = (const float*)d_in[3];

    _Float16* Qb = (_Float16*)d_ws;                        // 2 MB
    _Float16* Kb = Qb + (size_t)NB * NT * NH;              // 2 MB
    _Float16* Vt = Kb + (size_t)NB * NT * NH;              // 2 MB (transposed V)
    _Float16* Wt = Vt + (size_t)NB * NT * NH;              // 288 KB

    wtrans_kernel<<<dim3(48, 3), dim3(256), 0, stream>>>(Wq, Wk, Wv, Wt);
    proj_kernel<<<dim3(512), dim3(256), 0, stream>>>(x, Wt, Qb, Kb, Vt);
    attn_kernel<<<dim3(16, 16), dim3(256), 0, stream>>>(Qb, Kb, Vt, (float*)d_out);
}